// Round 5
// baseline (417.060 us; speedup 1.0000x reference)
//
#include <hip/hip_runtime.h>
#include <math.h>

// GAU attention: LN -> silu(x@W^T+b) x4 -> P=relu^2(QK^T/sqrt(T)) -> AV=P@V -> (U*AV)@Wo^T+bo
// R5: barrier-free register-streaming GEMMs (R4 structure) with bigger wave tiles.
// R4 measured 438 TF on the QKVU GEMM = 53.5 B/cyc/CU operand delivery — the
// vector-memory-path ceiling (m56: ~34.5 TB/s aggregate). Throughput is
// AI_wave x 56 B/cyc with AI = Wm*Wn/(Wm+Wn), so: wave tile 64x64 -> 64x128
// (TM=4,TN=8, AI 42.7) for QKVU/P and 64x96 (TM=4,TN=6, AI 38.4) for the
// N=768 GEMMs (keeps 256-block grids). No LDS, no __syncthreads in K-loop.

typedef __attribute__((ext_vector_type(8))) short short8;
typedef __attribute__((ext_vector_type(4))) float floatx4;

constexpr int HD = 768;
constexpr int TT = 2048;
constexpr long WElem = 589824;     // 768*768
constexpr long QKpb  = 1572864;    // 2048*768 shorts per batch
constexpr long Ppb   = 4194304;    // 2048*2048 shorts per batch

__device__ __forceinline__ short f2bf(float x) {
  unsigned u = __builtin_bit_cast(unsigned, x);
  u = u + 0x7fffu + ((u >> 16) & 1u);   // RNE
  return (short)(u >> 16);
}
__device__ __forceinline__ float bf2f(short s) {
  unsigned u = ((unsigned)(unsigned short)s) << 16;
  return __builtin_bit_cast(float, u);
}

// Packed fragment-order offset (in shorts) of element (i, c) of a row-major
// [R x C] matrix, CF = C/32. Fragment (i>>4, c>>5) is 512 shorts (1KB), lane-major:
// lane = ((c&31)>>3)*16 + (i&15), elem = c&7. A-packs and B-packs are identical.
__device__ __forceinline__ long p16(int i, int c, int CF) {
  return ((long)((i >> 4) * CF + (c >> 5))) * 512 +
         ((c & 31) >> 3) * 128 + (i & 15) * 8 + (c & 7);
}

// ---------------- LayerNorm + bf16 cast, writes x in packed-frag order ------------
__global__ __launch_bounds__(256) void ln_kernel(
    const float* __restrict__ x, const float* __restrict__ g,
    const float* __restrict__ b, short* __restrict__ out) {
  int row = blockIdx.x;
  const float* xr = x + (long)row * HD;
  int t = threadIdx.x;
  float v0 = xr[t], v1 = xr[t + 256], v2 = xr[t + 512];
  float s = v0 + v1 + v2;
  float ss = v0 * v0 + v1 * v1 + v2 * v2;
#pragma unroll
  for (int o = 32; o > 0; o >>= 1) {
    s += __shfl_down(s, o);
    ss += __shfl_down(ss, o);
  }
  __shared__ float red[8];
  int wid = t >> 6;
  if ((t & 63) == 0) { red[wid] = s; red[4 + wid] = ss; }
  __syncthreads();
  float S = red[0] + red[1] + red[2] + red[3];
  float SS = red[4] + red[5] + red[6] + red[7];
  float mean = S * (1.0f / HD);
  float var = SS * (1.0f / HD) - mean * mean;
  float rstd = rsqrtf(var + 1e-5f);
  out[p16(row, t, 24)]       = f2bf((v0 - mean) * rstd * g[t]       + b[t]);
  out[p16(row, t + 256, 24)] = f2bf((v1 - mean) * rstd * g[t + 256] + b[t + 256]);
  out[p16(row, t + 512, 24)] = f2bf((v2 - mean) * rstd * g[t + 512] + b[t + 512]);
}

// ---------------- fp32 -> packed bf16 weights + bias concat ------------------------
__global__ __launch_bounds__(256) void convert_kernel(
    const float* __restrict__ wu, const float* __restrict__ wq,
    const float* __restrict__ wk, const float* __restrict__ wv,
    const float* __restrict__ wo,
    const float* __restrict__ bu, const float* __restrict__ bq,
    const float* __restrict__ bk, const float* __restrict__ bv,
    short* __restrict__ Wb, float* __restrict__ bcat) {
  long i = (long)blockIdx.x * 256 + threadIdx.x;
  if (i < 5 * WElem) {
    int which = (int)(i / WElem);
    long off = i - (long)which * WElem;
    const float* src = which == 0 ? wu : which == 1 ? wq : which == 2 ? wk
                     : which == 3 ? wv : wo;
    int n = (int)(off / HD), k = (int)(off - (long)n * HD);
    Wb[(long)which * WElem + p16(n, k, 24)] = f2bf(src[off]);
  }
  if (i < 4 * HD) {
    int which = (int)(i / HD);
    int off = (int)(i - which * HD);
    const float* src = which == 0 ? bu : which == 1 ? bq : which == 2 ? bk : bv;
    bcat[i] = src[off];
  }
}

// ---------------- barrier-free streaming GEMM, 4 waves (2x2), wave tile TMxTN frags
// A, B in packed-frag order (KF = K/32 frags per row-strip). Wave computes
// (TM*16) x (TN*16) output. EPI 0: silu+bias -> U row-major / Qpack / Kpack / Vtpack.
// EPI 1: relu(acc*rs)^2 -> Ppack. EPI 2: acc*U -> Gpack. EPI 3: acc+bias -> fp32.
template <int EPI, int TM, int TN, int KF>
__global__ __launch_bounds__(256, 2) void wgemm(
    const short* __restrict__ Ag, const short* __restrict__ Bg,
    long sAz, long sBz,
    short* __restrict__ o0, short* __restrict__ o1,
    short* __restrict__ o2, short* __restrict__ o3,
    float* __restrict__ outf, const float* __restrict__ bias,
    const short* __restrict__ umul) {
  int z = blockIdx.z;
  int t = threadIdx.x, w = t >> 6, lane = t & 63;
  int qd = lane >> 4, l15 = lane & 15;
  int mf0 = (blockIdx.y * 2 + (w >> 1)) * TM;
  int nf0 = (blockIdx.x * 2 + (w & 1)) * TN;
  const short* aB = Ag + (long)z * sAz + (long)mf0 * KF * 512 + lane * 8;
  const short* bB = Bg + (long)z * sBz + (long)nf0 * KF * 512 + lane * 8;

  floatx4 acc[TM][TN] = {};
  short8 a[2][TM], b[2][TN];

#define LOADF(p, kf)                                                        \
  {                                                                         \
    _Pragma("unroll") for (int mi = 0; mi < TM; mi++)                       \
        a[p][mi] = *(const short8*)(aB + (mi * KF + (kf)) * 512);           \
    _Pragma("unroll") for (int ni = 0; ni < TN; ni++)                       \
        b[p][ni] = *(const short8*)(bB + (ni * KF + (kf)) * 512);           \
  }
#define MFMAS(p)                                                            \
  {                                                                         \
    _Pragma("unroll") for (int mi = 0; mi < TM; mi++)                       \
        _Pragma("unroll") for (int ni = 0; ni < TN; ni++)                   \
            acc[mi][ni] = __builtin_amdgcn_mfma_f32_16x16x32_bf16(          \
                a[p][mi], b[p][ni], acc[mi][ni], 0, 0, 0);                  \
  }

  LOADF(0, 0);
#pragma unroll 2
  for (int kf = 0; kf < KF - 1; ++kf) {
    LOADF((kf + 1) & 1, kf + 1);
    MFMAS(kf & 1);
  }
  MFMAS((KF - 1) & 1);
#undef LOADF
#undef MFMAS

  // epilogue: lane holds D[row = qd*4+r][col = l15] per 16x16 frag
#pragma unroll
  for (int mi = 0; mi < TM; mi++)
#pragma unroll
    for (int ni = 0; ni < TN; ni++) {
      int mB = (mf0 + mi) * 16 + qd * 4;
      int col = (nf0 + ni) * 16 + l15;
#pragma unroll
      for (int r = 0; r < 4; r++) {
        int m = mB + r;
        float v = acc[mi][ni][r];
        if constexpr (EPI == 0) {
          v += bias[col];
          v = v / (1.0f + __expf(-v));  // silu
          short sv = f2bf(v);
          int which = col / HD;
          int d = col - which * HD;
          int batch = m >> 11, i = m & (TT - 1);
          if (which == 0)      o0[(long)m * HD + d] = sv;                      // U row-major
          else if (which == 1) o1[(long)batch * QKpb + p16(i, d, 24)] = sv;    // Q pack
          else if (which == 2) o2[(long)batch * QKpb + p16(i, d, 24)] = sv;    // K pack
          else                 o3[(long)batch * QKpb + p16(d, i, 64)] = sv;    // Vt pack
        } else if constexpr (EPI == 1) {
          v *= 0.022097086912079608f;   // 1/sqrt(2048)
          v = fmaxf(v, 0.0f);
          v = v * v;
          o0[(long)z * Ppb + p16(m, col, 64)] = f2bf(v);                       // P pack
        } else if constexpr (EPI == 2) {
          long gm = (long)z * TT + m;
          float um = bf2f(umul[gm * HD + col]);
          o0[p16((int)gm, col, 24)] = f2bf(v * um);                            // G pack
        } else {
          outf[(long)m * HD + col] = v + bias[col];
        }
      }
    }
}

extern "C" void kernel_launch(void* const* d_in, const int* in_sizes, int n_in,
                              void* d_out, int out_size, void* d_ws, size_t ws_size,
                              hipStream_t stream) {
  (void)in_sizes; (void)n_in; (void)out_size; (void)ws_size;
  const float* hid = (const float*)d_in[0];
  const float* lng = (const float*)d_in[1];
  const float* lnb = (const float*)d_in[2];
  const float* Wu  = (const float*)d_in[3];
  const float* bu  = (const float*)d_in[4];
  const float* Wq  = (const float*)d_in[5];
  const float* bq  = (const float*)d_in[6];
  const float* Wk  = (const float*)d_in[7];
  const float* bk  = (const float*)d_in[8];
  const float* Wv  = (const float*)d_in[9];
  const float* bv  = (const float*)d_in[10];
  const float* Wo  = (const float*)d_in[11];
  const float* bo  = (const float*)d_in[12];

  // workspace layout (bytes); packed buffers
  char* ws = (char*)d_ws;
  short* Wb   = (short*)(ws);                 // 5*589824 bf16 = 5,898,240 B (packed)
  float* bcat = (float*)(ws + 5898240);       // 3072 fp32     =    12,288 B
  short* xbf  = (short*)(ws + 5910528);       // x pack, 12,582,912 B
  short* Ub   = (short*)(ws + 18493440);      // U row-major, 12,582,912 B
  short* Qb   = (short*)(ws + 31076352);      // Q pack, 12,582,912 B
  short* Kb   = (short*)(ws + 43659264);      // K pack, 12,582,912 B
  short* Vt   = (short*)(ws + 56242176);      // Vt pack, 12,582,912 B
  short* Pb   = (short*)(ws + 68825088);      // P pack, 33,554,432 B
  short* Gb   = (short*)(ws + 102379520);     // G pack, 12,582,912 B (total ~115 MB)

  convert_kernel<<<11520, 256, 0, stream>>>(Wu, Wq, Wk, Wv, Wo, bu, bq, bk, bv, Wb, bcat);
  ln_kernel<<<8192, 256, 0, stream>>>(hid, lng, lnb, xbf);

  // U,Q,K,V = silu(x @ Wcat^T + bcat): M=8192, N=3072, K=768. Wave 64x128.
  wgemm<0, 4, 8, 24><<<dim3(12, 64, 1), 256, 0, stream>>>(
      xbf, Wb, 0, 0, Ub, Qb, Kb, Vt, nullptr, bcat, nullptr);

  // P = relu(QK^T/sqrt(T))^2 per batch: M=N=2048, K=768. Wave 64x128.
  wgemm<1, 4, 8, 24><<<dim3(8, 16, 4), 256, 0, stream>>>(
      Qb, Kb, QKpb, QKpb, Pb, nullptr, nullptr, nullptr, nullptr, nullptr, nullptr);

  // G = (P @ V) * U per batch: M=2048, N=768, K=2048. Wave 64x96 (256 blocks).
  wgemm<2, 4, 6, 64><<<dim3(4, 16, 4), 256, 0, stream>>>(
      Pb, Vt, Ppb, QKpb, Gb, nullptr, nullptr, nullptr, nullptr, nullptr, Ub);

  // out = G @ Wo^T + bo: M=8192, N=768, K=768, fp32 out. Wave 64x96 (256 blocks).
  wgemm<3, 4, 6, 24><<<dim3(4, 64, 1), 256, 0, stream>>>(
      Gb, Wb + 4 * WElem, 0, 0, nullptr, nullptr, nullptr, nullptr,
      (float*)d_out, bo, nullptr);
}

// Round 6
// 296.946 us; speedup vs baseline: 1.4045x; 1.4045x over previous
//
#include <hip/hip_runtime.h>
#include <math.h>

// GAU attention: LN -> silu(x@W^T+b) x4 -> P=relu^2(QK^T/sqrt(T)) -> AV=P@V -> (U*AV)@Wo^T+bo
// R6: barrier-free register-streaming GEMMs (R4 structure, TM=TN=4, 72 VGPR) with
// distance-2 ping-pong prefetch: loads for kf+2 issued AFTER MFMAS(kf) into the
// buffer just consumed -> ~2x latency cover at zero register cost. No LDS, no
// __syncthreads in K-loop -> compiler emits fine-grained vmcnt(N) (AITER pattern).

typedef __attribute__((ext_vector_type(8))) short short8;
typedef __attribute__((ext_vector_type(4))) float floatx4;

constexpr int HD = 768;
constexpr int TT = 2048;
constexpr long WElem = 589824;     // 768*768
constexpr long QKpb  = 1572864;    // 2048*768 shorts per batch
constexpr long Ppb   = 4194304;    // 2048*2048 shorts per batch

__device__ __forceinline__ short f2bf(float x) {
  unsigned u = __builtin_bit_cast(unsigned, x);
  u = u + 0x7fffu + ((u >> 16) & 1u);   // RNE
  return (short)(u >> 16);
}
__device__ __forceinline__ float bf2f(short s) {
  unsigned u = ((unsigned)(unsigned short)s) << 16;
  return __builtin_bit_cast(float, u);
}

// Packed fragment-order offset (in shorts) of element (i, c) of a row-major
// [R x C] matrix, CF = C/32. Fragment (i>>4, c>>5) is 512 shorts (1KB), lane-major:
// lane = ((c&31)>>3)*16 + (i&15), elem = c&7. A-packs and B-packs are identical.
__device__ __forceinline__ long p16(int i, int c, int CF) {
  return ((long)((i >> 4) * CF + (c >> 5))) * 512 +
         ((c & 31) >> 3) * 128 + (i & 15) * 8 + (c & 7);
}

// ---------------- LayerNorm + bf16 cast, writes x in packed-frag order ------------
__global__ __launch_bounds__(256) void ln_kernel(
    const float* __restrict__ x, const float* __restrict__ g,
    const float* __restrict__ b, short* __restrict__ out) {
  int row = blockIdx.x;
  const float* xr = x + (long)row * HD;
  int t = threadIdx.x;
  float v0 = xr[t], v1 = xr[t + 256], v2 = xr[t + 512];
  float s = v0 + v1 + v2;
  float ss = v0 * v0 + v1 * v1 + v2 * v2;
#pragma unroll
  for (int o = 32; o > 0; o >>= 1) {
    s += __shfl_down(s, o);
    ss += __shfl_down(ss, o);
  }
  __shared__ float red[8];
  int wid = t >> 6;
  if ((t & 63) == 0) { red[wid] = s; red[4 + wid] = ss; }
  __syncthreads();
  float S = red[0] + red[1] + red[2] + red[3];
  float SS = red[4] + red[5] + red[6] + red[7];
  float mean = S * (1.0f / HD);
  float var = SS * (1.0f / HD) - mean * mean;
  float rstd = rsqrtf(var + 1e-5f);
  out[p16(row, t, 24)]       = f2bf((v0 - mean) * rstd * g[t]       + b[t]);
  out[p16(row, t + 256, 24)] = f2bf((v1 - mean) * rstd * g[t + 256] + b[t + 256]);
  out[p16(row, t + 512, 24)] = f2bf((v2 - mean) * rstd * g[t + 512] + b[t + 512]);
}

// ---------------- fp32 -> packed bf16 weights + bias concat ------------------------
__global__ __launch_bounds__(256) void convert_kernel(
    const float* __restrict__ wu, const float* __restrict__ wq,
    const float* __restrict__ wk, const float* __restrict__ wv,
    const float* __restrict__ wo,
    const float* __restrict__ bu, const float* __restrict__ bq,
    const float* __restrict__ bk, const float* __restrict__ bv,
    short* __restrict__ Wb, float* __restrict__ bcat) {
  long i = (long)blockIdx.x * 256 + threadIdx.x;
  if (i < 5 * WElem) {
    int which = (int)(i / WElem);
    long off = i - (long)which * WElem;
    const float* src = which == 0 ? wu : which == 1 ? wq : which == 2 ? wk
                     : which == 3 ? wv : wo;
    int n = (int)(off / HD), k = (int)(off - (long)n * HD);
    Wb[(long)which * WElem + p16(n, k, 24)] = f2bf(src[off]);
  }
  if (i < 4 * HD) {
    int which = (int)(i / HD);
    int off = (int)(i - which * HD);
    const float* src = which == 0 ? bu : which == 1 ? bq : which == 2 ? bk : bv;
    bcat[i] = src[off];
  }
}

// ---------------- barrier-free streaming GEMM, 4 waves (2x2), wave tile 64x64 ------
// A, B in packed-frag order (KF = K/32 frags per row-strip). Wave computes 64x64.
// Distance-2 ping-pong prefetch: MFMAS(kf) then LOADF(kf&1, kf+2).
// EPI 0: silu+bias -> U row-major / Qpack / Kpack / Vtpack.
// EPI 1: relu(acc*rs)^2 -> Ppack. EPI 2: acc*U -> Gpack. EPI 3: acc+bias -> fp32.
template <int EPI, int KF>
__global__ __launch_bounds__(256, 3) void wgemm(
    const short* __restrict__ Ag, const short* __restrict__ Bg,
    long sAz, long sBz,
    short* __restrict__ o0, short* __restrict__ o1,
    short* __restrict__ o2, short* __restrict__ o3,
    float* __restrict__ outf, const float* __restrict__ bias,
    const short* __restrict__ umul) {
  constexpr int TM = 4, TN = 4;
  int z = blockIdx.z;
  int t = threadIdx.x, w = t >> 6, lane = t & 63;
  int qd = lane >> 4, l15 = lane & 15;
  int mf0 = (blockIdx.y * 2 + (w >> 1)) * TM;
  int nf0 = (blockIdx.x * 2 + (w & 1)) * TN;
  const short* aB = Ag + (long)z * sAz + (long)mf0 * KF * 512 + lane * 8;
  const short* bB = Bg + (long)z * sBz + (long)nf0 * KF * 512 + lane * 8;

  floatx4 acc[TM][TN] = {};
  short8 a[2][TM], b[2][TN];

#define LOADF(p, kf)                                                        \
  {                                                                         \
    _Pragma("unroll") for (int mi = 0; mi < TM; mi++)                       \
        a[p][mi] = *(const short8*)(aB + (mi * KF + (kf)) * 512);           \
    _Pragma("unroll") for (int ni = 0; ni < TN; ni++)                       \
        b[p][ni] = *(const short8*)(bB + (ni * KF + (kf)) * 512);           \
  }
#define MFMAS(p)                                                            \
  {                                                                         \
    _Pragma("unroll") for (int mi = 0; mi < TM; mi++)                       \
        _Pragma("unroll") for (int ni = 0; ni < TN; ni++)                   \
            acc[mi][ni] = __builtin_amdgcn_mfma_f32_16x16x32_bf16(          \
                a[p][mi], b[p][ni], acc[mi][ni], 0, 0, 0);                  \
  }

  LOADF(0, 0);
  LOADF(1, 1);
#pragma unroll 2
  for (int kf = 0; kf < KF; ++kf) {
    MFMAS(kf & 1);
    if (kf + 2 < KF) LOADF(kf & 1, kf + 2);   // refill the buffer just consumed
  }
#undef LOADF
#undef MFMAS

  // epilogue: lane holds D[row = qd*4+r][col = l15] per 16x16 frag
#pragma unroll
  for (int mi = 0; mi < TM; mi++)
#pragma unroll
    for (int ni = 0; ni < TN; ni++) {
      int mB = (mf0 + mi) * 16 + qd * 4;
      int col = (nf0 + ni) * 16 + l15;
#pragma unroll
      for (int r = 0; r < 4; r++) {
        int m = mB + r;
        float v = acc[mi][ni][r];
        if constexpr (EPI == 0) {
          v += bias[col];
          v = v / (1.0f + __expf(-v));  // silu
          short sv = f2bf(v);
          int which = col / HD;
          int d = col - which * HD;
          int batch = m >> 11, i = m & (TT - 1);
          if (which == 0)      o0[(long)m * HD + d] = sv;                      // U row-major
          else if (which == 1) o1[(long)batch * QKpb + p16(i, d, 24)] = sv;    // Q pack
          else if (which == 2) o2[(long)batch * QKpb + p16(i, d, 24)] = sv;    // K pack
          else                 o3[(long)batch * QKpb + p16(d, i, 64)] = sv;    // Vt pack
        } else if constexpr (EPI == 1) {
          v *= 0.022097086912079608f;   // 1/sqrt(2048)
          v = fmaxf(v, 0.0f);
          v = v * v;
          o0[(long)z * Ppb + p16(m, col, 64)] = f2bf(v);                       // P pack
        } else if constexpr (EPI == 2) {
          long gm = (long)z * TT + m;
          float um = bf2f(umul[gm * HD + col]);
          o0[p16((int)gm, col, 24)] = f2bf(v * um);                            // G pack
        } else {
          outf[(long)m * HD + col] = v + bias[col];
        }
      }
    }
}

extern "C" void kernel_launch(void* const* d_in, const int* in_sizes, int n_in,
                              void* d_out, int out_size, void* d_ws, size_t ws_size,
                              hipStream_t stream) {
  (void)in_sizes; (void)n_in; (void)out_size; (void)ws_size;
  const float* hid = (const float*)d_in[0];
  const float* lng = (const float*)d_in[1];
  const float* lnb = (const float*)d_in[2];
  const float* Wu  = (const float*)d_in[3];
  const float* bu  = (const float*)d_in[4];
  const float* Wq  = (const float*)d_in[5];
  const float* bq  = (const float*)d_in[6];
  const float* Wk  = (const float*)d_in[7];
  const float* bk  = (const float*)d_in[8];
  const float* Wv  = (const float*)d_in[9];
  const float* bv  = (const float*)d_in[10];
  const float* Wo  = (const float*)d_in[11];
  const float* bo  = (const float*)d_in[12];

  // workspace layout (bytes); packed buffers
  char* ws = (char*)d_ws;
  short* Wb   = (short*)(ws);                 // 5*589824 bf16 = 5,898,240 B (packed)
  float* bcat = (float*)(ws + 5898240);       // 3072 fp32     =    12,288 B
  short* xbf  = (short*)(ws + 5910528);       // x pack, 12,582,912 B
  short* Ub   = (short*)(ws + 18493440);      // U row-major, 12,582,912 B
  short* Qb   = (short*)(ws + 31076352);      // Q pack, 12,582,912 B
  short* Kb   = (short*)(ws + 43659264);      // K pack, 12,582,912 B
  short* Vt   = (short*)(ws + 56242176);      // Vt pack, 12,582,912 B
  short* Pb   = (short*)(ws + 68825088);      // P pack, 33,554,432 B
  short* Gb   = (short*)(ws + 102379520);     // G pack, 12,582,912 B (total ~115 MB)

  convert_kernel<<<11520, 256, 0, stream>>>(Wu, Wq, Wk, Wv, Wo, bu, bq, bk, bv, Wb, bcat);
  ln_kernel<<<8192, 256, 0, stream>>>(hid, lng, lnb, xbf);

  // U,Q,K,V = silu(x @ Wcat^T + bcat): M=8192, N=3072, K=768 (KF=24)
  wgemm<0, 24><<<dim3(24, 64, 1), 256, 0, stream>>>(
      xbf, Wb, 0, 0, Ub, Qb, Kb, Vt, nullptr, bcat, nullptr);

  // P = relu(QK^T/sqrt(T))^2 per batch: M=N=2048, K=768 (KF=24)
  wgemm<1, 24><<<dim3(16, 16, 4), 256, 0, stream>>>(
      Qb, Kb, QKpb, QKpb, Pb, nullptr, nullptr, nullptr, nullptr, nullptr, nullptr);

  // G = (P @ V) * U per batch: M=2048, N=768, K=2048 (KF=64)
  wgemm<2, 64><<<dim3(6, 16, 4), 256, 0, stream>>>(
      Pb, Vt, Ppb, QKpb, Gb, nullptr, nullptr, nullptr, nullptr, nullptr, Ub);

  // out = G @ Wo^T + bo: M=8192, N=768, K=768 (KF=24), fp32 out
  wgemm<3, 24><<<dim3(6, 64, 1), 256, 0, stream>>>(
      Gb, Wb + 4 * WElem, 0, 0, nullptr, nullptr, nullptr, nullptr,
      (float*)d_out, bo, nullptr);
}

// Round 7
// 277.742 us; speedup vs baseline: 1.5016x; 1.0691x over previous
//
#include <hip/hip_runtime.h>
#include <math.h>

// GAU attention: LN -> silu(x@W^T+b) x4 -> P=relu^2(QK^T/sqrt(T)) -> AV=P@V -> (U*AV)@Wo^T+bo
// R7: R6 barrier-free register-streaming GEMMs + XCD-aware block remap.
// 1-D grid; flat%8 = XCD (round-robin dispatch). Each XCD gets a contiguous
// by-stripe (A-stripe ~1.6MB L2-resident) and sweeps bx slowly (B-block resident)
// -> steady-state L2 hits (~200cyc) fully covered by distance-2 ping-pong prefetch.

typedef __attribute__((ext_vector_type(8))) short short8;
typedef __attribute__((ext_vector_type(4))) float floatx4;

constexpr int HD = 768;
constexpr int TT = 2048;
constexpr long WElem = 589824;     // 768*768
constexpr long QKpb  = 1572864;    // 2048*768 shorts per batch
constexpr long Ppb   = 4194304;    // 2048*2048 shorts per batch

__device__ __forceinline__ short f2bf(float x) {
  unsigned u = __builtin_bit_cast(unsigned, x);
  u = u + 0x7fffu + ((u >> 16) & 1u);   // RNE
  return (short)(u >> 16);
}
__device__ __forceinline__ float bf2f(short s) {
  unsigned u = ((unsigned)(unsigned short)s) << 16;
  return __builtin_bit_cast(float, u);
}

// Packed fragment-order offset (in shorts) of element (i, c) of a row-major
// [R x C] matrix, CF = C/32. Fragment (i>>4, c>>5) is 512 shorts (1KB), lane-major.
__device__ __forceinline__ long p16(int i, int c, int CF) {
  return ((long)((i >> 4) * CF + (c >> 5))) * 512 +
         ((c & 31) >> 3) * 128 + (i & 15) * 8 + (c & 7);
}

// ---------------- LayerNorm + bf16 cast, writes x in packed-frag order ------------
__global__ __launch_bounds__(256) void ln_kernel(
    const float* __restrict__ x, const float* __restrict__ g,
    const float* __restrict__ b, short* __restrict__ out) {
  int row = blockIdx.x;
  const float* xr = x + (long)row * HD;
  int t = threadIdx.x;
  float v0 = xr[t], v1 = xr[t + 256], v2 = xr[t + 512];
  float s = v0 + v1 + v2;
  float ss = v0 * v0 + v1 * v1 + v2 * v2;
#pragma unroll
  for (int o = 32; o > 0; o >>= 1) {
    s += __shfl_down(s, o);
    ss += __shfl_down(ss, o);
  }
  __shared__ float red[8];
  int wid = t >> 6;
  if ((t & 63) == 0) { red[wid] = s; red[4 + wid] = ss; }
  __syncthreads();
  float S = red[0] + red[1] + red[2] + red[3];
  float SS = red[4] + red[5] + red[6] + red[7];
  float mean = S * (1.0f / HD);
  float var = SS * (1.0f / HD) - mean * mean;
  float rstd = rsqrtf(var + 1e-5f);
  out[p16(row, t, 24)]       = f2bf((v0 - mean) * rstd * g[t]       + b[t]);
  out[p16(row, t + 256, 24)] = f2bf((v1 - mean) * rstd * g[t + 256] + b[t + 256]);
  out[p16(row, t + 512, 24)] = f2bf((v2 - mean) * rstd * g[t + 512] + b[t + 512]);
}

// ---------------- fp32 -> packed bf16 weights + bias concat ------------------------
__global__ __launch_bounds__(256) void convert_kernel(
    const float* __restrict__ wu, const float* __restrict__ wq,
    const float* __restrict__ wk, const float* __restrict__ wv,
    const float* __restrict__ wo,
    const float* __restrict__ bu, const float* __restrict__ bq,
    const float* __restrict__ bk, const float* __restrict__ bv,
    short* __restrict__ Wb, float* __restrict__ bcat) {
  long i = (long)blockIdx.x * 256 + threadIdx.x;
  if (i < 5 * WElem) {
    int which = (int)(i / WElem);
    long off = i - (long)which * WElem;
    const float* src = which == 0 ? wu : which == 1 ? wq : which == 2 ? wk
                     : which == 3 ? wv : wo;
    int n = (int)(off / HD), k = (int)(off - (long)n * HD);
    Wb[(long)which * WElem + p16(n, k, 24)] = f2bf(src[off]);
  }
  if (i < 4 * HD) {
    int which = (int)(i / HD);
    int off = (int)(i - which * HD);
    const float* src = which == 0 ? bu : which == 1 ? bq : which == 2 ? bk : bv;
    bcat[i] = src[off];
  }
}

// ---------------- barrier-free streaming GEMM, 4 waves (2x2), wave tile 64x64 ------
// 1-D grid of GX*GY*GZ blocks. XCD-aware decode: xcd = flat&7 owns a contiguous
// by-stripe of 8 (GZ==1: by = xcd*8+byo over GY=64; GZ==4: z = xcd>>1,
// by = (xcd&1)*8+byo over GY=16); bx sweeps slowest within the XCD.
// Distance-2 ping-pong prefetch; no LDS, no __syncthreads in K-loop.
template <int EPI, int KF, int GZ>
__global__ __launch_bounds__(256, 3) void wgemm(
    const short* __restrict__ Ag, const short* __restrict__ Bg,
    long sAz, long sBz,
    short* __restrict__ o0, short* __restrict__ o1,
    short* __restrict__ o2, short* __restrict__ o3,
    float* __restrict__ outf, const float* __restrict__ bias,
    const short* __restrict__ umul) {
  constexpr int TM = 4, TN = 4;
  int f = blockIdx.x;
  int xcd = f & 7, i = f >> 3;
  int bx = i >> 3, byo = i & 7;
  int z, by;
  if constexpr (GZ == 1) { z = 0;        by = xcd * 8 + byo; }
  else                   { z = xcd >> 1; by = (xcd & 1) * 8 + byo; }

  int t = threadIdx.x, w = t >> 6, lane = t & 63;
  int qd = lane >> 4, l15 = lane & 15;
  int mf0 = (by * 2 + (w >> 1)) * TM;
  int nf0 = (bx * 2 + (w & 1)) * TN;
  const short* aB = Ag + (long)z * sAz + (long)mf0 * KF * 512 + lane * 8;
  const short* bB = Bg + (long)z * sBz + (long)nf0 * KF * 512 + lane * 8;

  floatx4 acc[TM][TN] = {};
  short8 a[2][TM], b[2][TN];

#define LOADF(p, kf)                                                        \
  {                                                                         \
    _Pragma("unroll") for (int mi = 0; mi < TM; mi++)                       \
        a[p][mi] = *(const short8*)(aB + (mi * KF + (kf)) * 512);           \
    _Pragma("unroll") for (int ni = 0; ni < TN; ni++)                       \
        b[p][ni] = *(const short8*)(bB + (ni * KF + (kf)) * 512);           \
  }
#define MFMAS(p)                                                            \
  {                                                                         \
    _Pragma("unroll") for (int mi = 0; mi < TM; mi++)                       \
        _Pragma("unroll") for (int ni = 0; ni < TN; ni++)                   \
            acc[mi][ni] = __builtin_amdgcn_mfma_f32_16x16x32_bf16(          \
                a[p][mi], b[p][ni], acc[mi][ni], 0, 0, 0);                  \
  }

  LOADF(0, 0);
  LOADF(1, 1);
#pragma unroll 2
  for (int kf = 0; kf < KF; ++kf) {
    MFMAS(kf & 1);
    if (kf + 2 < KF) LOADF(kf & 1, kf + 2);   // refill the buffer just consumed
  }
#undef LOADF
#undef MFMAS

  // epilogue: lane holds D[row = qd*4+r][col = l15] per 16x16 frag
#pragma unroll
  for (int mi = 0; mi < TM; mi++)
#pragma unroll
    for (int ni = 0; ni < TN; ni++) {
      int mB = (mf0 + mi) * 16 + qd * 4;
      int col = (nf0 + ni) * 16 + l15;
#pragma unroll
      for (int r = 0; r < 4; r++) {
        int m = mB + r;
        float v = acc[mi][ni][r];
        if constexpr (EPI == 0) {
          v += bias[col];
          v = v / (1.0f + __expf(-v));  // silu
          short sv = f2bf(v);
          int which = col / HD;
          int d = col - which * HD;
          int batch = m >> 11, ii = m & (TT - 1);
          if (which == 0)      o0[(long)m * HD + d] = sv;                      // U row-major
          else if (which == 1) o1[(long)batch * QKpb + p16(ii, d, 24)] = sv;   // Q pack
          else if (which == 2) o2[(long)batch * QKpb + p16(ii, d, 24)] = sv;   // K pack
          else                 o3[(long)batch * QKpb + p16(d, ii, 64)] = sv;   // Vt pack
        } else if constexpr (EPI == 1) {
          v *= 0.022097086912079608f;   // 1/sqrt(2048)
          v = fmaxf(v, 0.0f);
          v = v * v;
          o0[(long)z * Ppb + p16(m, col, 64)] = f2bf(v);                       // P pack
        } else if constexpr (EPI == 2) {
          long gm = (long)z * TT + m;
          float um = bf2f(umul[gm * HD + col]);
          o0[p16((int)gm, col, 24)] = f2bf(v * um);                            // G pack
        } else {
          outf[(long)m * HD + col] = v + bias[col];
        }
      }
    }
}

extern "C" void kernel_launch(void* const* d_in, const int* in_sizes, int n_in,
                              void* d_out, int out_size, void* d_ws, size_t ws_size,
                              hipStream_t stream) {
  (void)in_sizes; (void)n_in; (void)out_size; (void)ws_size;
  const float* hid = (const float*)d_in[0];
  const float* lng = (const float*)d_in[1];
  const float* lnb = (const float*)d_in[2];
  const float* Wu  = (const float*)d_in[3];
  const float* bu  = (const float*)d_in[4];
  const float* Wq  = (const float*)d_in[5];
  const float* bq  = (const float*)d_in[6];
  const float* Wk  = (const float*)d_in[7];
  const float* bk  = (const float*)d_in[8];
  const float* Wv  = (const float*)d_in[9];
  const float* bv  = (const float*)d_in[10];
  const float* Wo  = (const float*)d_in[11];
  const float* bo  = (const float*)d_in[12];

  // workspace layout (bytes); packed buffers
  char* ws = (char*)d_ws;
  short* Wb   = (short*)(ws);                 // 5*589824 bf16 = 5,898,240 B (packed)
  float* bcat = (float*)(ws + 5898240);       // 3072 fp32     =    12,288 B
  short* xbf  = (short*)(ws + 5910528);       // x pack, 12,582,912 B
  short* Ub   = (short*)(ws + 18493440);      // U row-major, 12,582,912 B
  short* Qb   = (short*)(ws + 31076352);      // Q pack, 12,582,912 B
  short* Kb   = (short*)(ws + 43659264);      // K pack, 12,582,912 B
  short* Vt   = (short*)(ws + 56242176);      // Vt pack, 12,582,912 B
  short* Pb   = (short*)(ws + 68825088);      // P pack, 33,554,432 B
  short* Gb   = (short*)(ws + 102379520);     // G pack, 12,582,912 B (total ~115 MB)

  convert_kernel<<<11520, 256, 0, stream>>>(Wu, Wq, Wk, Wv, Wo, bu, bq, bk, bv, Wb, bcat);
  ln_kernel<<<8192, 256, 0, stream>>>(hid, lng, lnb, xbf);

  // U,Q,K,V = silu(x @ Wcat^T + bcat): M=8192 (GY=64), N=3072 (GX=24), K=768
  wgemm<0, 24, 1><<<1536, 256, 0, stream>>>(
      xbf, Wb, 0, 0, Ub, Qb, Kb, Vt, nullptr, bcat, nullptr);

  // P = relu(QK^T/sqrt(T))^2 per batch: GY=16, GX=16, GZ=4, K=768
  wgemm<1, 24, 4><<<1024, 256, 0, stream>>>(
      Qb, Kb, QKpb, QKpb, Pb, nullptr, nullptr, nullptr, nullptr, nullptr, nullptr);

  // G = (P @ V) * U per batch: GY=16, GX=6, GZ=4, K=2048
  wgemm<2, 64, 4><<<384, 256, 0, stream>>>(
      Pb, Vt, Ppb, QKpb, Gb, nullptr, nullptr, nullptr, nullptr, nullptr, Ub);

  // out = G @ Wo^T + bo: GY=64, GX=6, GZ=1, K=768, fp32 out
  wgemm<3, 24, 1><<<384, 256, 0, stream>>>(
      Gb, Wb + 4 * WElem, 0, 0, nullptr, nullptr, nullptr, nullptr,
      (float*)d_out, bo, nullptr);
}